// Round 5
// baseline (405.309 us; speedup 1.0000x reference)
//
#include <hip/hip_runtime.h>
#include <hip/hip_bf16.h>

#define NTOK 4096   // 64*64 tokens per batch
#define NPOOL 1024  // 32*32 pooled tokens per batch

using short8 = __attribute__((ext_vector_type(8))) short;
using f32x4  = __attribute__((ext_vector_type(4))) float;

__device__ __forceinline__ unsigned short f2bf(float f) {
  __hip_bfloat16 h = __float2bfloat16(f);
  return __builtin_bit_cast(unsigned short, h);
}

// Map local tile row m (0..63) to a global x row such that rows 4*p..4*p+3 are
// the 2x2 pooling corners of pooled row bx*16+p.
__device__ __forceinline__ int pool_row(int bx, int m) {
  int pg = bx * 16 + (m >> 2);
  int corner = m & 3;
  int batch = pg >> 10;
  int pl = pg & 1023;
  int pi = pl >> 5, pj = pl & 31;
  return (batch << 12) + ((2 * pi + (corner >> 1)) << 6) + 2 * pj + (corner & 1);
}

// Pack weights: wcatT[384][512] = [f(64) | g(64) | h(256)]^T bf16; woT[512][256] bf16.
__global__ __launch_bounds__(256) void pack_w(const float* __restrict__ wf,
                                              const float* __restrict__ wg,
                                              const float* __restrict__ wh,
                                              const float* __restrict__ wo,
                                              unsigned short* __restrict__ wcatT,
                                              unsigned short* __restrict__ woT) {
  int i = blockIdx.x * 256 + threadIdx.x;
  if (i < 384 * 512) {
    int n = i >> 9, k = i & 511;
    float v = (n < 64) ? wf[k * 64 + n]
            : (n < 128) ? wg[k * 64 + (n - 64)]
                        : wh[k * 256 + (n - 128)];
    wcatT[i] = f2bf(v);
  } else if (i < 384 * 512 + 512 * 256) {
    int j = i - 384 * 512;
    int n = j >> 8, k = j & 255;
    woT[j] = f2bf(wo[(size_t)k * 512 + n]);
  }
}

// Fused f/g/h projection, MFMA, register-prefetch pipelined.
__global__ __launch_bounds__(256) void fgh_proj(const float* __restrict__ x,
                                                const unsigned short* __restrict__ wcatT,
                                                unsigned short* __restrict__ fB,
                                                unsigned short* __restrict__ gB,
                                                unsigned short* __restrict__ hT) {
  __shared__ unsigned short lds[17920];  // As[64][40] @0 ; WsT[384][40] @2560
  const int tid = threadIdx.x;
  const int bx = blockIdx.x;
  const int wave = tid >> 6, lane = tid & 63;
  const int col = lane & 15, rgrp = lane >> 4;

  // staging assignments (fixed per thread)
  const int mA = tid >> 3, k4A = (tid & 7) << 2;       // x: rows mA, mA+32
  const int rowA0 = pool_row(bx, mA), rowA1 = pool_row(bx, mA + 32);
  const int nW = tid >> 2, k8W = (tid & 3) << 3;       // w: rows nW + 64*r

  f32x4 acc[4][6];
#pragma unroll
  for (int mt = 0; mt < 4; ++mt)
#pragma unroll
    for (int nt = 0; nt < 6; ++nt) acc[mt][nt] = (f32x4){0.f, 0.f, 0.f, 0.f};

  float4 xR[2];
  uint4 wR[6];
  // prologue: chunk 0
  xR[0] = *(const float4*)(x + (size_t)rowA0 * 512 + k4A);
  xR[1] = *(const float4*)(x + (size_t)rowA1 * 512 + k4A);
#pragma unroll
  for (int r = 0; r < 6; ++r)
    wR[r] = *(const uint4*)(wcatT + (size_t)(nW + r * 64) * 512 + k8W);

  for (int kt = 0; kt < 16; ++kt) {
    __syncthreads();
    {
      ushort4 o4;
      o4.x = f2bf(xR[0].x); o4.y = f2bf(xR[0].y); o4.z = f2bf(xR[0].z); o4.w = f2bf(xR[0].w);
      *(ushort4*)&lds[mA * 40 + k4A] = o4;
      o4.x = f2bf(xR[1].x); o4.y = f2bf(xR[1].y); o4.z = f2bf(xR[1].z); o4.w = f2bf(xR[1].w);
      *(ushort4*)&lds[(mA + 32) * 40 + k4A] = o4;
#pragma unroll
      for (int r = 0; r < 6; ++r)
        *(uint4*)&lds[2560 + (nW + r * 64) * 40 + k8W] = wR[r];
    }
    __syncthreads();
    if (kt < 15) {  // prefetch next chunk; latency overlaps MFMA below
      int ko = (kt + 1) * 32;
      xR[0] = *(const float4*)(x + (size_t)rowA0 * 512 + ko + k4A);
      xR[1] = *(const float4*)(x + (size_t)rowA1 * 512 + ko + k4A);
#pragma unroll
      for (int r = 0; r < 6; ++r)
        wR[r] = *(const uint4*)(wcatT + (size_t)(nW + r * 64) * 512 + ko + k8W);
    }

    short8 am[4];
#pragma unroll
    for (int mt = 0; mt < 4; ++mt)
      am[mt] = *(const short8*)&lds[(mt * 16 + col) * 40 + rgrp * 8];
#pragma unroll
    for (int nt = 0; nt < 6; ++nt) {
      short8 bn = *(const short8*)&lds[2560 + (wave * 96 + nt * 16 + col) * 40 + rgrp * 8];
#pragma unroll
      for (int mt = 0; mt < 4; ++mt)
        acc[mt][nt] = __builtin_amdgcn_mfma_f32_16x16x32_bf16(am[mt], bn, acc[mt][nt], 0, 0, 0);
    }
  }
  __syncthreads();

  // epilogue assembly in LDS (alias over staging)
  unsigned short* gO = lds;          // [64][72]
  unsigned short* fO = lds + 4608;   // [16][72]
  unsigned short* hO = lds + 5760;   // [256][24]
#pragma unroll
  for (int mt = 0; mt < 4; ++mt) {
#pragma unroll
    for (int nt = 0; nt < 6; ++nt) {
      int n = wave * 96 + nt * 16 + col;
      f32x4 a = acc[mt][nt];
      if (n < 64) {
        float mx = fmaxf(fmaxf(a[0], a[1]), fmaxf(a[2], a[3]));
        fO[(mt * 4 + rgrp) * 72 + n] = f2bf(mx);
      } else if (n < 128) {
#pragma unroll
        for (int reg = 0; reg < 4; ++reg)
          gO[(mt * 16 + rgrp * 4 + reg) * 72 + (n - 64)] = f2bf(a[reg]);
      } else {
        float mx = fmaxf(fmaxf(a[0], a[1]), fmaxf(a[2], a[3]));
        hO[(n - 128) * 24 + (mt * 4 + rgrp)] = f2bf(mx);
      }
    }
  }
  __syncthreads();

  const int b = bx >> 6, pkb = (bx & 63) * 16;
#pragma unroll
  for (int r = 0; r < 2; ++r) {  // g: 64 rows x 64 ch (rows permuted)
    int idx = tid + r * 256;
    int m = idx >> 3, d8 = (idx & 7) << 3;
    *(uint4*)(gB + (size_t)pool_row(bx, m) * 64 + d8) = *(const uint4*)&gO[m * 72 + d8];
  }
  if (tid < 128) {               // f: 16 pooled rows x 64 ch
    int pr = tid >> 3, d8 = (tid & 7) << 3;
    *(uint4*)(fB + (size_t)(bx * 16 + pr) * 64 + d8) = *(const uint4*)&fO[pr * 72 + d8];
  }
#pragma unroll
  for (int r = 0; r < 2; ++r) {  // hT: 256 dv x 16 pooled
    int idx = tid + r * 256;
    int dv = idx >> 1, p8 = (idx & 1) << 3;
    *(uint4*)(hT + (((size_t)b * 256 + dv) << 10) + pkb + p8) = *(const uint4*)&hO[dv * 24 + p8];
  }
}

// MFMA flash attention, register-prefetch pipelined; bf16 output o[32768][256].
__global__ __launch_bounds__(256) void attn_mfma(const __hip_bfloat16* __restrict__ G,
                                                 const __hip_bfloat16* __restrict__ F,
                                                 const __hip_bfloat16* __restrict__ HT,
                                                 unsigned short* __restrict__ O) {
  __shared__ __hip_bfloat16 gS[64][72];   // [q][d]
  __shared__ __hip_bfloat16 fS[64][72];   // [k][d]
  __shared__ __hip_bfloat16 hS[256][72];  // [dv][k]
  __shared__ __hip_bfloat16 pS[64][72];   // [q][k]

  const int tid = threadIdx.x;
  const int wave = tid >> 6, lane = tid & 63;
  const int col = lane & 15;
  const int rgrp = lane >> 4;
  const int b = blockIdx.x >> 6, qt = blockIdx.x & 63;

  const __hip_bfloat16* Gb = G + ((size_t)b * NTOK + qt * 64) * 64;
  const __hip_bfloat16* Fb = F + (size_t)b * NPOOL * 64;
  const __hip_bfloat16* Hb = HT + (size_t)b * 256 * NPOOL;

#pragma unroll
  for (int r = 0; r < 2; ++r) {
    int j = tid + r * 256;
    int q = j >> 3, d8 = (j & 7) << 3;
    *(uint4*)&gS[q][d8] = *(const uint4*)(Gb + (size_t)q * 64 + d8);
  }
  __syncthreads();

  short8 ag[2];
#pragma unroll
  for (int ks = 0; ks < 2; ++ks)
    ag[ks] = *(const short8*)&gS[wave * 16 + col][ks * 32 + rgrp * 8];

  f32x4 oacc[16];
#pragma unroll
  for (int t = 0; t < 16; ++t) oacc[t] = (f32x4){0.f, 0.f, 0.f, 0.f};
  float m_run[4], l_run[4];
#pragma unroll
  for (int r = 0; r < 4; ++r) { m_run[r] = -1e30f; l_run[r] = 0.f; }

  // staging assignments (fixed): f rows fk, fk+32; h rows hdv + 32*r
  const int fk = tid >> 3, e8 = (tid & 7) << 3;
  uint4 fR[2], hR[8];
  // prologue: chunk 0
  fR[0] = *(const uint4*)(Fb + (size_t)fk * 64 + e8);
  fR[1] = *(const uint4*)(Fb + (size_t)(fk + 32) * 64 + e8);
#pragma unroll
  for (int r = 0; r < 8; ++r)
    hR[r] = *(const uint4*)(Hb + (size_t)(fk + 32 * r) * NPOOL + e8);

  for (int kc = 0; kc < 16; ++kc) {
    __syncthreads();  // all waves done reading fS/hS from prev chunk
    *(uint4*)&fS[fk][e8] = fR[0];
    *(uint4*)&fS[fk + 32][e8] = fR[1];
#pragma unroll
    for (int r = 0; r < 8; ++r) *(uint4*)&hS[fk + 32 * r][e8] = hR[r];
    __syncthreads();
    if (kc < 15) {  // prefetch next chunk; latency overlaps compute below
      int ko = (kc + 1) * 64;
      fR[0] = *(const uint4*)(Fb + (size_t)(ko + fk) * 64 + e8);
      fR[1] = *(const uint4*)(Fb + (size_t)(ko + fk + 32) * 64 + e8);
#pragma unroll
      for (int r = 0; r < 8; ++r)
        hR[r] = *(const uint4*)(Hb + (size_t)(fk + 32 * r) * NPOOL + ko + e8);
    }

    f32x4 s[4];
#pragma unroll
    for (int t = 0; t < 4; ++t) s[t] = (f32x4){0.f, 0.f, 0.f, 0.f};
#pragma unroll
    for (int ks = 0; ks < 2; ++ks) {
#pragma unroll
      for (int t = 0; t < 4; ++t) {
        short8 bf = *(const short8*)&fS[t * 16 + col][ks * 32 + rgrp * 8];
        s[t] = __builtin_amdgcn_mfma_f32_16x16x32_bf16(ag[ks], bf, s[t], 0, 0, 0);
      }
    }

    float cm[4];
#pragma unroll
    for (int r = 0; r < 4; ++r) {
      cm[r] = fmaxf(fmaxf(s[0][r], s[1][r]), fmaxf(s[2][r], s[3][r]));
#pragma unroll
      for (int msk = 1; msk < 16; msk <<= 1) cm[r] = fmaxf(cm[r], __shfl_xor(cm[r], msk));
    }
    float alpha[4], rs[4];
#pragma unroll
    for (int r = 0; r < 4; ++r) {
      float mn = fmaxf(m_run[r], cm[r]);
      alpha[r] = __expf(m_run[r] - mn);
      m_run[r] = mn;
      rs[r] = 0.f;
    }
    const int prow = wave * 16 + rgrp * 4;
#pragma unroll
    for (int t = 0; t < 4; ++t) {
#pragma unroll
      for (int r = 0; r < 4; ++r) {
        float p = __expf(s[t][r] - m_run[r]);
        rs[r] += p;
        pS[prow + r][t * 16 + col] = __float2bfloat16(p);
      }
    }
#pragma unroll
    for (int r = 0; r < 4; ++r) {
#pragma unroll
      for (int msk = 1; msk < 16; msk <<= 1) rs[r] += __shfl_xor(rs[r], msk);
      l_run[r] = alpha[r] * l_run[r] + rs[r];
    }

#pragma unroll
    for (int t = 0; t < 16; ++t) {
#pragma unroll
      for (int r = 0; r < 4; ++r) oacc[t][r] *= alpha[r];
    }

    short8 ap[2];
#pragma unroll
    for (int ks = 0; ks < 2; ++ks)
      ap[ks] = *(const short8*)&pS[wave * 16 + col][ks * 32 + rgrp * 8];
#pragma unroll
    for (int t = 0; t < 16; ++t) {
#pragma unroll
      for (int ks = 0; ks < 2; ++ks) {
        short8 bh = *(const short8*)&hS[t * 16 + col][ks * 32 + rgrp * 8];
        oacc[t] = __builtin_amdgcn_mfma_f32_16x16x32_bf16(ap[ks], bh, oacc[t], 0, 0, 0);
      }
    }
  }

  // epilogue: normalize, assemble bf16 in LDS (alias hS), coalesced store
  float inv[4];
#pragma unroll
  for (int r = 0; r < 4; ++r) inv[r] = 1.0f / l_run[r];
  __syncthreads();
  unsigned short* oS = (unsigned short*)&hS[0][0];  // [64][264]
  const int qrow = wave * 16 + rgrp * 4;
#pragma unroll
  for (int t = 0; t < 16; ++t) {
#pragma unroll
    for (int r = 0; r < 4; ++r)
      oS[(qrow + r) * 264 + t * 16 + col] = f2bf(oacc[t][r] * inv[r]);
  }
  __syncthreads();
  unsigned short* Ob = O + ((size_t)b * NTOK + qt * 64) * 256;
#pragma unroll
  for (int r = 0; r < 8; ++r) {
    int idx = tid + r * 256;
    int q = idx >> 5, d8 = (idx & 31) << 3;
    *(uint4*)(Ob + (size_t)q * 256 + d8) = *(const uint4*)&oS[q * 264 + d8];
  }
}

// MFMA out-GEMM, register-prefetch pipelined: out = gamma*(o @ wo) + x.
__global__ __launch_bounds__(256) void gemm_out_mfma(const unsigned short* __restrict__ Obf,
                                                     const unsigned short* __restrict__ woT,
                                                     const float* __restrict__ Xres,
                                                     const float* __restrict__ gamma,
                                                     float* __restrict__ Out) {
  __shared__ unsigned short lds[23040];  // As[64][40] @0 ; WsT[512][40] @2560
  const int tid = threadIdx.x;
  const int bx = blockIdx.x;
  const int wave = tid >> 6, lane = tid & 63;
  const int col = lane & 15, rgrp = lane >> 4;

  const int mA = tid >> 2, k8 = (tid & 3) << 3;  // A row mA; B rows mA + 64*r

  f32x4 acc[4][8];
#pragma unroll
  for (int mt = 0; mt < 4; ++mt)
#pragma unroll
    for (int nt = 0; nt < 8; ++nt) acc[mt][nt] = (f32x4){0.f, 0.f, 0.f, 0.f};

  uint4 aR, bR[8];
  aR = *(const uint4*)(Obf + ((size_t)bx * 64 + mA) * 256 + k8);
#pragma unroll
  for (int r = 0; r < 8; ++r)
    bR[r] = *(const uint4*)(woT + (size_t)(mA + r * 64) * 256 + k8);

  for (int kt = 0; kt < 8; ++kt) {
    __syncthreads();
    *(uint4*)&lds[mA * 40 + k8] = aR;
#pragma unroll
    for (int r = 0; r < 8; ++r)
      *(uint4*)&lds[2560 + (mA + r * 64) * 40 + k8] = bR[r];
    __syncthreads();
    if (kt < 7) {
      int ko = (kt + 1) * 32;
      aR = *(const uint4*)(Obf + ((size_t)bx * 64 + mA) * 256 + ko + k8);
#pragma unroll
      for (int r = 0; r < 8; ++r)
        bR[r] = *(const uint4*)(woT + (size_t)(mA + r * 64) * 256 + ko + k8);
    }

    short8 am[4];
#pragma unroll
    for (int mt = 0; mt < 4; ++mt)
      am[mt] = *(const short8*)&lds[(mt * 16 + col) * 40 + rgrp * 8];
#pragma unroll
    for (int nt = 0; nt < 8; ++nt) {
      short8 bn = *(const short8*)&lds[2560 + (wave * 128 + nt * 16 + col) * 40 + rgrp * 8];
#pragma unroll
      for (int mt = 0; mt < 4; ++mt)
        acc[mt][nt] = __builtin_amdgcn_mfma_f32_16x16x32_bf16(am[mt], bn, acc[mt][nt], 0, 0, 0);
    }
  }

  float gm = gamma[0];
#pragma unroll
  for (int mt = 0; mt < 4; ++mt) {
#pragma unroll
    for (int nt = 0; nt < 8; ++nt) {
      int n = wave * 128 + nt * 16 + col;
#pragma unroll
      for (int reg = 0; reg < 4; ++reg) {
        size_t row = (size_t)bx * 64 + mt * 16 + rgrp * 4 + reg;
        size_t off = row * 512 + n;
        Out[off] = gm * acc[mt][nt][reg] + Xres[off];
      }
    }
  }
}

extern "C" void kernel_launch(void* const* d_in, const int* in_sizes, int n_in,
                              void* d_out, int out_size, void* d_ws, size_t ws_size,
                              hipStream_t stream) {
  (void)in_sizes; (void)n_in; (void)out_size; (void)ws_size;
  const float* x     = (const float*)d_in[0];
  const float* wf    = (const float*)d_in[1];
  const float* wg    = (const float*)d_in[2];
  const float* wh    = (const float*)d_in[3];
  const float* wo    = (const float*)d_in[4];
  const float* gamma = (const float*)d_in[5];
  float* out = (float*)d_out;

  unsigned short* ws = (unsigned short*)d_ws;
  unsigned short* oB    = ws;               // [32768][256] bf16
  unsigned short* gB    = ws + 8388608;     // [32768][64]
  unsigned short* fB    = ws + 10485760;    // [8192][64]
  unsigned short* hT    = ws + 11010048;    // [8][256][1024]
  unsigned short* wcatT = ws + 13107200;    // [384][512]
  unsigned short* woT   = ws + 13303808;    // [512][256]

  dim3 blk(256);
  pack_w<<<1280, blk, 0, stream>>>(wf, wg, wh, wo, wcatT, woT);
  fgh_proj<<<512, blk, 0, stream>>>(x, wcatT, fB, gB, hT);
  attn_mfma<<<512, blk, 0, stream>>>((const __hip_bfloat16*)gB, (const __hip_bfloat16*)fB,
                                     (const __hip_bfloat16*)hT, oB);
  gemm_out_mfma<<<512, blk, 0, stream>>>(oB, woT, x, gamma, out);
}

// Round 6
// 290.215 us; speedup vs baseline: 1.3966x; 1.3966x over previous
//
#include <hip/hip_runtime.h>
#include <hip/hip_bf16.h>

#define NTOK 4096   // 64*64 tokens per batch
#define NPOOL 1024  // 32*32 pooled tokens per batch

using short8  = __attribute__((ext_vector_type(8))) short;
using ushort8 = __attribute__((ext_vector_type(8))) unsigned short;
using f32x4   = __attribute__((ext_vector_type(4))) float;

__device__ __forceinline__ unsigned short f2bf(float f) {
  __hip_bfloat16 h = __float2bfloat16(f);
  return __builtin_bit_cast(unsigned short, h);
}
__device__ __forceinline__ float bf2f(unsigned short u) {
  unsigned int t = ((unsigned int)u) << 16;
  return __builtin_bit_cast(float, t);
}

// Map local tile row m (0..31) to a global x row such that rows 4*p..4*p+3 are
// the 2x2 pooling corners of pooled row bx*8+p.
__device__ __forceinline__ int pool_row8(int bx, int m) {
  int pg = bx * 8 + (m >> 2);
  int corner = m & 3;
  int batch = pg >> 10;
  int pl = pg & 1023;
  int pi = pl >> 5, pj = pl & 31;
  return (batch << 12) + ((2 * pi + (corner >> 1)) << 6) + 2 * pj + (corner & 1);
}

// Pack weights: wcatT[384][512] = [f(64) | g(64) | h(256)]^T bf16; woT[512][256] bf16.
__global__ __launch_bounds__(256) void pack_w(const float* __restrict__ wf,
                                              const float* __restrict__ wg,
                                              const float* __restrict__ wh,
                                              const float* __restrict__ wo,
                                              unsigned short* __restrict__ wcatT,
                                              unsigned short* __restrict__ woT) {
  int i = blockIdx.x * 256 + threadIdx.x;
  if (i < 384 * 512) {
    int n = i >> 9, k = i & 511;
    float v = (n < 64) ? wf[k * 64 + n]
            : (n < 128) ? wg[k * 64 + (n - 64)]
                        : wh[k * 256 + (n - 128)];
    wcatT[i] = f2bf(v);
  } else if (i < 384 * 512 + 512 * 256) {
    int j = i - 384 * 512;
    int n = j >> 8, k = j & 255;
    woT[j] = f2bf(wo[(size_t)k * 512 + n]);
  }
}

// Fused f/g/h projection, MFMA. Block = 32 x-rows x 384 cols (1024 blocks -> 4/CU).
__global__ __launch_bounds__(256) void fgh_proj(const float* __restrict__ x,
                                                const unsigned short* __restrict__ wcatT,
                                                unsigned short* __restrict__ fB,
                                                unsigned short* __restrict__ gB,
                                                unsigned short* __restrict__ hT) {
  __shared__ unsigned short lds[16640];  // As[32][40] @0 ; WsT[384][40] @1280
  const int tid = threadIdx.x;
  const int bx = blockIdx.x;
  const int wave = tid >> 6, lane = tid & 63;
  const int col = lane & 15, rgrp = lane >> 4;

  const int mA = tid >> 3, k4A = (tid & 7) << 2;   // x stage: row mA, 4 floats
  const int rowA = pool_row8(bx, mA);
  const int nW = tid >> 2, k8W = (tid & 3) << 3;   // w stage: rows nW + 64*r

  f32x4 acc[2][6];
#pragma unroll
  for (int mt = 0; mt < 2; ++mt)
#pragma unroll
    for (int nt = 0; nt < 6; ++nt) acc[mt][nt] = (f32x4){0.f, 0.f, 0.f, 0.f};

  for (int kt = 0; kt < 16; ++kt) {
    __syncthreads();
    {
      float4 v = *(const float4*)(x + (size_t)rowA * 512 + kt * 32 + k4A);
      ushort4 o4;
      o4.x = f2bf(v.x); o4.y = f2bf(v.y); o4.z = f2bf(v.z); o4.w = f2bf(v.w);
      *(ushort4*)&lds[mA * 40 + k4A] = o4;
#pragma unroll
      for (int r = 0; r < 6; ++r)
        *(uint4*)&lds[1280 + (nW + r * 64) * 40 + k8W] =
            *(const uint4*)(wcatT + (size_t)(nW + r * 64) * 512 + kt * 32 + k8W);
    }
    __syncthreads();

    short8 am[2];
#pragma unroll
    for (int mt = 0; mt < 2; ++mt)
      am[mt] = *(const short8*)&lds[(mt * 16 + col) * 40 + rgrp * 8];
#pragma unroll
    for (int nt = 0; nt < 6; ++nt) {
      short8 bn = *(const short8*)&lds[1280 + (wave * 96 + nt * 16 + col) * 40 + rgrp * 8];
#pragma unroll
      for (int mt = 0; mt < 2; ++mt)
        acc[mt][nt] = __builtin_amdgcn_mfma_f32_16x16x32_bf16(am[mt], bn, acc[mt][nt], 0, 0, 0);
    }
  }
  __syncthreads();

  // epilogue assembly in LDS (alias over staging)
  unsigned short* gO = lds;          // [32][72]
  unsigned short* fO = lds + 2304;   // [8][72]
  unsigned short* hO = lds + 2880;   // [256][16]
#pragma unroll
  for (int mt = 0; mt < 2; ++mt) {
#pragma unroll
    for (int nt = 0; nt < 6; ++nt) {
      int n = wave * 96 + nt * 16 + col;
      f32x4 a = acc[mt][nt];
      if (n < 64) {
        float mx = fmaxf(fmaxf(a[0], a[1]), fmaxf(a[2], a[3]));
        fO[(mt * 4 + rgrp) * 72 + n] = f2bf(mx);
      } else if (n < 128) {
#pragma unroll
        for (int reg = 0; reg < 4; ++reg)
          gO[(mt * 16 + rgrp * 4 + reg) * 72 + (n - 64)] = f2bf(a[reg]);
      } else {
        float mx = fmaxf(fmaxf(a[0], a[1]), fmaxf(a[2], a[3]));
        hO[(n - 128) * 16 + (mt * 4 + rgrp)] = f2bf(mx);
      }
    }
  }
  __syncthreads();

  const int b = bx >> 7, pkb = (bx & 127) * 8;
  {  // g: 32 rows x 64 ch (rows permuted)
    int m = tid >> 3, d8 = (tid & 7) << 3;
    *(uint4*)(gB + (size_t)pool_row8(bx, m) * 64 + d8) = *(const uint4*)&gO[m * 72 + d8];
  }
  if (tid < 64) {               // f: 8 pooled rows x 64 ch
    int pr = tid >> 3, d8 = (tid & 7) << 3;
    *(uint4*)(fB + (size_t)(bx * 8 + pr) * 64 + d8) = *(const uint4*)&fO[pr * 72 + d8];
  }
  {  // hT: 256 dv x 8 pooled
    int dv = tid;
    *(uint4*)(hT + (((size_t)b * 256 + dv) << 10) + pkb) = *(const uint4*)&hO[dv * 16];
  }
}

// MFMA flash attention, 2-way K-split. Block = (batch, 64q tile, ksplit); 1024 blocks.
// K-chunk = 32 keys; each split covers 512 keys and writes normalized partial O + (m,l).
__global__ __launch_bounds__(256) void attn_split(const __hip_bfloat16* __restrict__ G,
                                                  const __hip_bfloat16* __restrict__ F,
                                                  const __hip_bfloat16* __restrict__ HT,
                                                  unsigned short* __restrict__ Op,
                                                  float* __restrict__ ML) {
  __shared__ unsigned short lds[19712];
  // gS[64][72] @0 ; fS[32][72] @4608 ; hS[256][40] @6912 ; pS[64][40] @17152
  const int tid = threadIdx.x;
  const int wave = tid >> 6, lane = tid & 63;
  const int col = lane & 15, rgrp = lane >> 4;
  const int bx = blockIdx.x;
  const int split = bx & 1, qt = (bx >> 1) & 63, b = bx >> 7;

  const __hip_bfloat16* Gb = G + ((size_t)b * NTOK + qt * 64) * 64;
  const __hip_bfloat16* Fb = F + ((size_t)b * NPOOL + split * 512) * 64;
  const __hip_bfloat16* Hb = HT + (size_t)b * 256 * NPOOL + split * 512;

  // stage g tile [64][64]
#pragma unroll
  for (int r = 0; r < 2; ++r) {
    int j = tid + r * 256;
    int q = j >> 3, d8 = (j & 7) << 3;
    *(uint4*)&lds[q * 72 + d8] = *(const uint4*)(Gb + (size_t)q * 64 + d8);
  }
  __syncthreads();

  short8 ag[2];
#pragma unroll
  for (int ks = 0; ks < 2; ++ks)
    ag[ks] = *(const short8*)&lds[(wave * 16 + col) * 72 + ks * 32 + rgrp * 8];

  f32x4 oacc[16];
#pragma unroll
  for (int t = 0; t < 16; ++t) oacc[t] = (f32x4){0.f, 0.f, 0.f, 0.f};
  float m_run[4], l_run[4];
#pragma unroll
  for (int r = 0; r < 4; ++r) { m_run[r] = -1e30f; l_run[r] = 0.f; }

  const int fk = tid >> 3, fd8 = (tid & 7) << 3;   // f stage: 32 keys x 64 d

  for (int kc = 0; kc < 16; ++kc) {
    __syncthreads();
    // stage f chunk [32 keys][64 d]
    *(uint4*)&lds[4608 + fk * 72 + fd8] =
        *(const uint4*)(Fb + (size_t)(kc * 32 + fk) * 64 + fd8);
    // stage h chunk [256 dv][32 k]
#pragma unroll
    for (int r = 0; r < 4; ++r) {
      int j = tid + r * 256;
      int dv = j >> 2, k8 = (j & 3) << 3;
      *(uint4*)&lds[6912 + dv * 40 + k8] =
          *(const uint4*)(Hb + (size_t)dv * NPOOL + kc * 32 + k8);
    }
    __syncthreads();

    // QK^T: S[16q x 32k] per wave (2 key-tiles x 2 K-steps)
    f32x4 s[2];
#pragma unroll
    for (int t = 0; t < 2; ++t) s[t] = (f32x4){0.f, 0.f, 0.f, 0.f};
#pragma unroll
    for (int ks = 0; ks < 2; ++ks) {
#pragma unroll
      for (int t = 0; t < 2; ++t) {
        short8 bf = *(const short8*)&lds[4608 + (t * 16 + col) * 72 + ks * 32 + rgrp * 8];
        s[t] = __builtin_amdgcn_mfma_f32_16x16x32_bf16(ag[ks], bf, s[t], 0, 0, 0);
      }
    }

    // online softmax; lane owns rows wave*16+rgrp*4+r, cols t*16+col
    float cm[4];
#pragma unroll
    for (int r = 0; r < 4; ++r) {
      cm[r] = fmaxf(s[0][r], s[1][r]);
#pragma unroll
      for (int msk = 1; msk < 16; msk <<= 1) cm[r] = fmaxf(cm[r], __shfl_xor(cm[r], msk));
    }
    float alpha[4], rs[4];
#pragma unroll
    for (int r = 0; r < 4; ++r) {
      float mn = fmaxf(m_run[r], cm[r]);
      alpha[r] = __expf(m_run[r] - mn);
      m_run[r] = mn;
      rs[r] = 0.f;
    }
    const int prow = wave * 16 + rgrp * 4;
#pragma unroll
    for (int t = 0; t < 2; ++t) {
#pragma unroll
      for (int r = 0; r < 4; ++r) {
        float p = __expf(s[t][r] - m_run[r]);
        rs[r] += p;
        lds[17152 + (prow + r) * 40 + t * 16 + col] = f2bf(p);
      }
    }
#pragma unroll
    for (int r = 0; r < 4; ++r) {
#pragma unroll
      for (int msk = 1; msk < 16; msk <<= 1) rs[r] += __shfl_xor(rs[r], msk);
      l_run[r] = alpha[r] * l_run[r] + rs[r];
    }

#pragma unroll
    for (int t = 0; t < 16; ++t) {
#pragma unroll
      for (int r = 0; r < 4; ++r) oacc[t][r] *= alpha[r];
    }

    // PV: O[16q x 256dv] += P[16x32] @ h[32x256]
    short8 ap = *(const short8*)&lds[17152 + (wave * 16 + col) * 40 + rgrp * 8];
#pragma unroll
    for (int t = 0; t < 16; ++t) {
      short8 bh = *(const short8*)&lds[6912 + (t * 16 + col) * 40 + rgrp * 8];
      oacc[t] = __builtin_amdgcn_mfma_f32_16x16x32_bf16(ap, bh, oacc[t], 0, 0, 0);
    }
  }

  // epilogue: normalize, write partial O (bf16) and per-row (m,l)
  float inv[4];
#pragma unroll
  for (int r = 0; r < 4; ++r) inv[r] = 1.0f / l_run[r];
  __syncthreads();
  const int qrow = wave * 16 + rgrp * 4;
#pragma unroll
  for (int t = 0; t < 16; ++t) {
#pragma unroll
    for (int r = 0; r < 4; ++r)
      lds[(qrow + r) * 264 + t * 16 + col] = f2bf(oacc[t][r] * inv[r]);
  }
  if (col == 0) {
    float2* mlp = (float2*)ML;
    const size_t rowg = (size_t)b * NTOK + qt * 64 + qrow;
#pragma unroll
    for (int r = 0; r < 4; ++r)
      mlp[(size_t)split * 32768 + rowg + r] = make_float2(m_run[r], l_run[r]);
  }
  __syncthreads();
  unsigned short* Ob = Op + (size_t)split * 8388608 + ((size_t)b * NTOK + qt * 64) * 256;
#pragma unroll
  for (int r = 0; r < 8; ++r) {
    int idx = tid + r * 256;
    int q = idx >> 5, d8 = (idx & 31) << 3;
    *(uint4*)(Ob + (size_t)q * 256 + d8) = *(const uint4*)&lds[q * 264 + d8];
  }
}

// Blend the two K-split partials: o = c0*O0 + c1*O1 (in-place into Op split 0).
__global__ __launch_bounds__(256) void combine_k(unsigned short* __restrict__ Op,
                                                 const float* __restrict__ ML) {
  int idx = blockIdx.x * 256 + threadIdx.x;   // 1,048,576 threads
  int row = idx >> 5, d8 = (idx & 31) << 3;
  const float2* mlp = (const float2*)ML;
  float2 a = mlp[row], bml = mlp[32768 + row];
  float M = fmaxf(a.x, bml.x);
  float w0 = __expf(a.x - M) * a.y;
  float w1 = __expf(bml.x - M) * bml.y;
  float inv = 1.0f / (w0 + w1);
  float c0 = w0 * inv, c1 = w1 * inv;
  size_t off = (size_t)row * 256 + d8;
  ushort8 u0 = *(const ushort8*)(Op + off);
  ushort8 u1 = *(const ushort8*)(Op + 8388608 + off);
  ushort8 o;
#pragma unroll
  for (int i = 0; i < 8; ++i)
    o[i] = f2bf(c0 * bf2f(u0[i]) + c1 * bf2f(u1[i]));
  *(ushort8*)(Op + off) = o;
}

// MFMA out-GEMM, N-split: out = gamma*(o @ wo) + x. Grid (512, 2) -> 4 blocks/CU.
__global__ __launch_bounds__(256) void gemm_out_mfma(const unsigned short* __restrict__ Obf,
                                                     const unsigned short* __restrict__ woT,
                                                     const float* __restrict__ Xres,
                                                     const float* __restrict__ gamma,
                                                     float* __restrict__ Out) {
  __shared__ unsigned short lds[12800];  // As[64][40] @0 ; WsT[256][40] @2560
  const int tid = threadIdx.x;
  const int bx = blockIdx.x, by = blockIdx.y;
  const int wave = tid >> 6, lane = tid & 63;
  const int col = lane & 15, rgrp = lane >> 4;

  const int mA = tid >> 2, k8 = (tid & 3) << 3;

  f32x4 acc[4][4];
#pragma unroll
  for (int mt = 0; mt < 4; ++mt)
#pragma unroll
    for (int nt = 0; nt < 4; ++nt) acc[mt][nt] = (f32x4){0.f, 0.f, 0.f, 0.f};

  for (int kt = 0; kt < 8; ++kt) {
    __syncthreads();
    *(uint4*)&lds[mA * 40 + k8] =
        *(const uint4*)(Obf + ((size_t)bx * 64 + mA) * 256 + kt * 32 + k8);
#pragma unroll
    for (int r = 0; r < 4; ++r) {
      int idx = tid + r * 256;
      int n = idx >> 2, k8w = (idx & 3) << 3;
      *(uint4*)&lds[2560 + n * 40 + k8w] =
          *(const uint4*)(woT + (size_t)(by * 256 + n) * 256 + kt * 32 + k8w);
    }
    __syncthreads();

    short8 am[4];
#pragma unroll
    for (int mt = 0; mt < 4; ++mt)
      am[mt] = *(const short8*)&lds[(mt * 16 + col) * 40 + rgrp * 8];
#pragma unroll
    for (int nt = 0; nt < 4; ++nt) {
      short8 bn = *(const short8*)&lds[2560 + (wave * 64 + nt * 16 + col) * 40 + rgrp * 8];
#pragma unroll
      for (int mt = 0; mt < 4; ++mt)
        acc[mt][nt] = __builtin_amdgcn_mfma_f32_16x16x32_bf16(am[mt], bn, acc[mt][nt], 0, 0, 0);
    }
  }

  float gm = gamma[0];
#pragma unroll
  for (int mt = 0; mt < 4; ++mt) {
#pragma unroll
    for (int nt = 0; nt < 4; ++nt) {
      int n = by * 256 + wave * 64 + nt * 16 + col;
#pragma unroll
      for (int reg = 0; reg < 4; ++reg) {
        size_t row = (size_t)bx * 64 + mt * 16 + rgrp * 4 + reg;
        size_t off = row * 512 + n;
        Out[off] = gm * acc[mt][nt][reg] + Xres[off];
      }
    }
  }
}

extern "C" void kernel_launch(void* const* d_in, const int* in_sizes, int n_in,
                              void* d_out, int out_size, void* d_ws, size_t ws_size,
                              hipStream_t stream) {
  (void)in_sizes; (void)n_in; (void)out_size; (void)ws_size;
  const float* x     = (const float*)d_in[0];
  const float* wf    = (const float*)d_in[1];
  const float* wg    = (const float*)d_in[2];
  const float* wh    = (const float*)d_in[3];
  const float* wo    = (const float*)d_in[4];
  const float* gamma = (const float*)d_in[5];
  float* out = (float*)d_out;

  unsigned short* ws = (unsigned short*)d_ws;
  unsigned short* gB    = ws;               // [32768][64]
  unsigned short* fB    = ws + 2097152;     // [8192][64]
  unsigned short* hT    = ws + 2621440;     // [8][256][1024]
  unsigned short* wcatT = ws + 4718592;     // [384][512]
  unsigned short* woT   = ws + 4915200;     // [512][256]
  unsigned short* Op    = ws + 5046272;     // [2][32768][256] partials; split 0 becomes o
  float*          ML    = (float*)(ws + 21823488);  // [2][32768] float2

  dim3 blk(256);
  pack_w<<<1280, blk, 0, stream>>>(wf, wg, wh, wo, wcatT, woT);
  fgh_proj<<<1024, blk, 0, stream>>>(x, wcatT, fB, gB, hT);
  attn_split<<<1024, blk, 0, stream>>>((const __hip_bfloat16*)gB, (const __hip_bfloat16*)fB,
                                       (const __hip_bfloat16*)hT, Op, ML);
  combine_k<<<4096, blk, 0, stream>>>(Op, ML);
  gemm_out_mfma<<<dim3(512, 2), blk, 0, stream>>>(Op, woT, x, gamma, out);
}